// Round 6
// baseline (1537.656 us; speedup 1.0000x reference)
//
#include <hip/hip_runtime.h>
#include <stdint.h>

#define NM 128    // matrix dim / electrons
#define NT 1024   // 16 waves; waves 0-7 -> matrix 0, waves 8-15 -> matrix 1
                  // within a matrix: wave w owns cols [16w..16w+15]; lane l owns rows l, l+64

typedef float v2f __attribute__((ext_vector_type(2)));

__device__ __forceinline__ float readlane_f(float v, int lane) {
    return __int_as_float(__builtin_amdgcn_readlane(__float_as_int(v), lane));
}

// Full 64-lane unsigned max via DPP (VALU pipe); result valid in lane 63.
__device__ __forceinline__ unsigned wave_max_dpp(unsigned x) {
    int v = (int)x;
#define DPP_STEP(ctrl) \
    { int o = __builtin_amdgcn_update_dpp(0, v, ctrl, 0xf, 0xf, true); \
      v = ((unsigned)o > (unsigned)v) ? o : v; }
    DPP_STEP(0x111)  // row_shr:1
    DPP_STEP(0x112)  // row_shr:2
    DPP_STEP(0x114)  // row_shr:4
    DPP_STEP(0x118)  // row_shr:8
    DPP_STEP(0x142)  // row_bcast:15
    DPP_STEP(0x143)  // row_bcast:31
#undef DPP_STEP
    return (unsigned)v;
}

__device__ __forceinline__ unsigned pack_key(float v, int r) {
    // monotone in |v|; drop 6 mantissa LSBs to make room for the 7-bit row id
    return (((__float_as_uint(v) & 0x7fffffffu) >> 6) << 7) | (unsigned)r;
}

// max(ka,kb) over the wave, broadcast to all lanes (uniform result)
__device__ __forceinline__ unsigned argmax_bcast(unsigned ka, unsigned kb) {
    const unsigned m = wave_max_dpp(ka > kb ? ka : kb);
    return (unsigned)__builtin_amdgcn_readlane((int)m, 63);
}

// select s[B + 2*jb] for uniform jb in [0,8): cndmask tree, no dynamic indexing
template<int B>
__device__ __forceinline__ float sel8(const float (&s)[32], int jb) {
    const float a0 = (jb & 1) ? s[B + 2]  : s[B + 0];
    const float a1 = (jb & 1) ? s[B + 6]  : s[B + 4];
    const float a2 = (jb & 1) ? s[B + 10] : s[B + 8];
    const float a3 = (jb & 1) ? s[B + 14] : s[B + 12];
    const float b0 = (jb & 2) ? a1 : a0;
    const float b1 = (jb & 2) ? a3 : a2;
    return (jb & 4) ? b1 : b0;
}

// fused rank-2 update of a 16-column slab; P0LO/P1LO = pivot row in low half.
// Row-pair FMAs packed as v_pk_fma_f32 via elementwise_fma on v2f.
template<bool P0LO, bool P1LO>
__device__ __forceinline__ void update16(float (&s)[32], int p0l, int p1l,
                                         float lp1, v2f lm0, v2f lm1) {
#pragma unroll
    for (int j = 0; j < 16; ++j) {
        const float u0 = P0LO ? readlane_f(s[j], p0l) : readlane_f(s[j + 16], p0l);
        const float t1 = P1LO ? readlane_f(s[j], p1l) : readlane_f(s[j + 16], p1l);
        const float u1 = t1 - lp1 * u0;     // row p1 post-step-k
        v2f v; v.x = s[j]; v.y = s[j + 16];
        v = __builtin_elementwise_fma((v2f){-u0, -u0}, lm0, v);
        v = __builtin_elementwise_fma((v2f){-u1, -u1}, lm1, v);
        s[j] = v.x; s[j + 16] = v.y;
    }
}

__global__ __launch_bounds__(NT, 8)
void slater_logdet(const float* __restrict__ rs,
                   const float* __restrict__ kpts,
                   const float* __restrict__ csw,
                   const float* __restrict__ ssw,
                   float* __restrict__ out) {
    // per-matrix: pub[i] = {piv_2i, piv_2i+1, key_2i, key_2i+1} (write-once),
    // colv[parity][r] = {col 2i post-(2i-1), col 2i+1 post-2i}
    __shared__ __align__(16) float4 pub[2][NM / 2];
    __shared__ float2 colv[2][2][NM];
    __shared__ float redf[2][2];

    const int t   = threadIdx.x;
    const int mat = t >> 9;          // which matrix in this block
    const int tt  = t & 511;
    const int b   = (blockIdx.x << 1) | mat;
    const int w   = tt >> 6;         // wave id within matrix = column-slab id
    const int l   = t & 63;
    const int c0  = w << 4;
    const int r0  = l, r1 = l + 64;

    const float x0 = rs[(b * NM + r0) * 3 + 0];
    const float y0 = rs[(b * NM + r0) * 3 + 1];
    const float z0 = rs[(b * NM + r0) * 3 + 2];
    const float x1 = rs[(b * NM + r1) * 3 + 0];
    const float y1 = rs[(b * NM + r1) * 3 + 1];
    const float z1 = rs[(b * NM + r1) * 3 + 2];

    float s[32];   // s[j] = row r0 col c0+j ; s[j+16] = row r1 col c0+j
#pragma unroll
    for (int j = 0; j < 16; ++j) {
        const int m = c0 + j;  // wave-uniform -> scalar loads
        const float kx = kpts[m * 3 + 0], ky = kpts[m * 3 + 1], kz = kpts[m * 3 + 2];
        const float cw = csw[m], sw = ssw[m];
        float sn, cn;
        __sincosf(kx * x0 + ky * y0 + kz * z0, &sn, &cn);
        s[j] = cw * cn - sw * sn;
        __sincosf(kx * x1 + ky * y1 + kz * z1, &sn, &cn);
        s[j + 16] = cw * cn - sw * sn;
    }

    bool elim0 = false, elim1 = false;

    // ---- bootstrap: wave 0 of each matrix publishes steps 0 and 1 ----
    if (w == 0) {
        const float c0a = s[0], c0b = s[16];
        const float c1p = s[1], c1q = s[17];
        const unsigned key0 = argmax_bcast(pack_key(c0a, r0), pack_key(c0b, r1));
        const int p0 = (int)(key0 & 127u);
        const float piv0 = (p0 < 64) ? readlane_f(c0a, p0) : readlane_f(c0b, p0 - 64);
        const float u01  = (p0 < 64) ? readlane_f(c1p, p0) : readlane_f(c1q, p0 - 64);
        const float rcp0 = __builtin_amdgcn_rcpf(piv0);
        const bool e0 = (r0 == p0), e1 = (r1 == p0);
        const float l0a = e0 ? 0.0f : c0a * rcp0;
        const float l0b = e1 ? 0.0f : c0b * rcp0;
        const float c1a = c1p - l0a * u01;
        const float c1b = c1q - l0b * u01;
        const unsigned key1 = argmax_bcast(e0 ? 0u : pack_key(c1a, r0),
                                           e1 ? 0u : pack_key(c1b, r1));
        const int p1 = (int)(key1 & 127u);
        const float piv1 = (p1 < 64) ? readlane_f(c1a, p1) : readlane_f(c1b, p1 - 64);
        colv[mat][0][r0] = make_float2(c0a, c1a);
        colv[mat][0][r1] = make_float2(c0b, c1b);
        if (l == 0) pub[mat][0] = make_float4(piv0, piv1,
                                    __uint_as_float(key0), __uint_as_float(key1));
    }
    __syncthreads();

    // ---- main loop: one barrier per 2 elimination steps, 2 matrices/barrier ----
    for (int k = 0; k < NM - 2; k += 2) {
        if (c0 + 15 >= k + 2) {          // live slab; dead waves only barrier
            const int rd = k >> 1;
            const float4 pb = pub[mat][rd];
            const unsigned key0 = __float_as_uint(pb.z);
            const unsigned key1 = __float_as_uint(pb.w);
            const int p0 = (int)(key0 & 127u), p1 = (int)(key1 & 127u);
            const float rcp0 = __builtin_amdgcn_rcpf(pb.x);
            const float rcp1 = __builtin_amdgcn_rcpf(pb.y);
            const float2 ca = colv[mat][rd & 1][r0];
            const float2 cb = colv[mat][rd & 1][r1];
            elim0 |= (r0 == p0); elim1 |= (r1 == p0);
            const float l0a = elim0 ? 0.0f : ca.x * rcp0;
            const float l0b = elim1 ? 0.0f : cb.x * rcp0;
            elim0 |= (r0 == p1); elim1 |= (r1 == p1);
            const float l1a = elim0 ? 0.0f : ca.y * rcp1;
            const float l1b = elim1 ? 0.0f : cb.y * rcp1;
            const float lp1 = colv[mat][rd & 1][p1].x * rcp0;   // broadcast read
            const v2f lm0 = {l0a, l0b};
            const v2f lm1 = {l1a, l1b};

            const int p0u = __builtin_amdgcn_readfirstlane(p0);
            const int p1u = __builtin_amdgcn_readfirstlane(p1);
            if (p0u < 64) {
                if (p1u < 64) update16<true, true >(s, p0u,      p1u,      lp1, lm0, lm1);
                else          update16<true, false>(s, p0u,      p1u - 64, lp1, lm0, lm1);
            } else {
                if (p1u < 64) update16<false, true >(s, p0u - 64, p1u,      lp1, lm0, lm1);
                else          update16<false, false>(s, p0u - 64, p1u - 64, lp1, lm0, lm1);
            }

            // ---- look-ahead publish of steps k+2, k+3 (one owner wave/matrix) ----
            if (w == ((k + 2) >> 4)) {
                const int jb = ((k + 2) & 15) >> 1;        // uniform, even col pair
                const float c2a = sel8<0 >(s, jb), c2b = sel8<16>(s, jb);
                const float c3p = sel8<1 >(s, jb), c3q = sel8<17>(s, jb);
                const unsigned key2 = argmax_bcast(elim0 ? 0u : pack_key(c2a, r0),
                                                   elim1 ? 0u : pack_key(c2b, r1));
                const int p2 = (int)(key2 & 127u);
                const float piv2 = (p2 < 64) ? readlane_f(c2a, p2) : readlane_f(c2b, p2 - 64);
                const float u23  = (p2 < 64) ? readlane_f(c3p, p2) : readlane_f(c3q, p2 - 64);
                const float rcp2 = __builtin_amdgcn_rcpf(piv2);
                const bool e0 = elim0 || (r0 == p2), e1 = elim1 || (r1 == p2);
                const float l2a = e0 ? 0.0f : c2a * rcp2;
                const float l2b = e1 ? 0.0f : c2b * rcp2;
                const float c3a = c3p - l2a * u23;
                const float c3b = c3q - l2b * u23;
                const unsigned key3 = argmax_bcast(e0 ? 0u : pack_key(c3a, r0),
                                                   e1 ? 0u : pack_key(c3b, r1));
                const int p3 = (int)(key3 & 127u);
                const float piv3 = (p3 < 64) ? readlane_f(c3a, p3) : readlane_f(c3b, p3 - 64);
                colv[mat][(rd + 1) & 1][r0] = make_float2(c2a, c3a);
                colv[mat][(rd + 1) & 1][r1] = make_float2(c2b, c3b);
                if (l == 0) pub[mat][rd + 1] = make_float4(piv2, piv3,
                                 __uint_as_float(key2), __uint_as_float(key3));
            }
        }
        __syncthreads();
    }

    // ---- log|det| = sum log|piv_k| over the write-once pub array ----
    float lg = 0.0f;
    if (tt < NM) {
        const float4 pb = pub[mat][tt >> 1];
        const float pv = (tt & 1) ? pb.y : pb.x;
        lg = __logf(fabsf(pv));
    }
#pragma unroll
    for (int off = 32; off > 0; off >>= 1)
        lg += __shfl_xor(lg, off, 64);
    if ((t & 63) == 0 && w < 2) redf[mat][w] = lg;
    __syncthreads();
    if (tt == 0) out[b] = redf[mat][0] + redf[mat][1];
}

extern "C" void kernel_launch(void* const* d_in, const int* in_sizes, int n_in,
                              void* d_out, int out_size, void* d_ws, size_t ws_size,
                              hipStream_t stream) {
    const float* rs = (const float*)d_in[0];
    const float* kp = (const float*)d_in[1];
    const float* cs = (const float*)d_in[2];
    const float* ss = (const float*)d_in[3];
    float* out = (float*)d_out;
    const int batch = in_sizes[0] / (NM * 3);  // 4096
    slater_logdet<<<dim3(batch / 2), dim3(NT), 0, stream>>>(rs, kp, cs, ss, out);
}

// Round 7
// 559.401 us; speedup vs baseline: 2.7488x; 2.7488x over previous
//
#include <hip/hip_runtime.h>
#include <stdint.h>

#define NM 128    // matrix dim / electrons
#define NT 1024   // 16 waves per matrix; wave w owns cols [8w..8w+7]; lane l owns rows l, l+64
                  // lane state: sv[j] = (S[l][8w+j], S[l+64][8w+j])  -> 16 VGPRs of matrix

typedef float v2f __attribute__((ext_vector_type(2)));

__device__ __forceinline__ float readlane_f(float v, int lane) {
    return __int_as_float(__builtin_amdgcn_readlane(__float_as_int(v), lane));
}

// Full 64-lane unsigned max via DPP (VALU pipe); result valid in lane 63.
__device__ __forceinline__ unsigned wave_max_dpp(unsigned x) {
    int v = (int)x;
#define DPP_STEP(ctrl) \
    { int o = __builtin_amdgcn_update_dpp(0, v, ctrl, 0xf, 0xf, true); \
      v = ((unsigned)o > (unsigned)v) ? o : v; }
    DPP_STEP(0x111)  // row_shr:1
    DPP_STEP(0x112)  // row_shr:2
    DPP_STEP(0x114)  // row_shr:4
    DPP_STEP(0x118)  // row_shr:8
    DPP_STEP(0x142)  // row_bcast:15
    DPP_STEP(0x143)  // row_bcast:31
#undef DPP_STEP
    return (unsigned)v;
}

__device__ __forceinline__ unsigned pack_key(float v, int r) {
    // monotone in |v|; drop 6 mantissa LSBs to make room for the 7-bit row id
    return (((__float_as_uint(v) & 0x7fffffffu) >> 6) << 7) | (unsigned)r;
}

// max(ka,kb) over the wave, broadcast to all lanes (uniform result)
__device__ __forceinline__ unsigned argmax_bcast(unsigned ka, unsigned kb) {
    const unsigned m = wave_max_dpp(ka > kb ? ka : kb);
    return (unsigned)__builtin_amdgcn_readlane((int)m, 63);
}

// fused rank-2 update of an 8-column slab; P0LO/P1LO = pivot row in low half.
// lm0/lm1 are PRE-MULTIPLIED (l = colval * rcp(piv)), elim rows zeroed.
template<bool P0LO, bool P1LO>
__device__ __forceinline__ void update8(v2f (&sv)[8], int p0l, int p1l,
                                        float lp1, v2f lm0, v2f lm1) {
#pragma unroll
    for (int j = 0; j < 8; ++j) {
        const float u0 = P0LO ? readlane_f(sv[j].x, p0l) : readlane_f(sv[j].y, p0l);
        const float t1 = P1LO ? readlane_f(sv[j].x, p1l) : readlane_f(sv[j].y, p1l);
        const float u1 = t1 - lp1 * u0;     // row p1 post-step-k
        v2f v = sv[j];
        v = __builtin_elementwise_fma((v2f){-u0, -u0}, lm0, v);
        v = __builtin_elementwise_fma((v2f){-u1, -u1}, lm1, v);
        sv[j] = v;
    }
}

__global__ __launch_bounds__(NT, 8)
void slater_logdet(const float* __restrict__ rs,
                   const float* __restrict__ kpts,
                   const float* __restrict__ csw,
                   const float* __restrict__ ssw,
                   float* __restrict__ out) {
    // pub[i] = {piv_2i, piv_2i+1, key_2i, key_2i+1} — write-once per slot
    __shared__ __align__(16) float4 pub[NM / 2];
    // colv[parity][r] = PRE-MULTIPLIED multipliers {col 2i, col 2i+1} for row r
    __shared__ float2 colv[2][NM];
    __shared__ float redf[2];

    const int t  = threadIdx.x;
    const int b  = blockIdx.x;
    const int w  = t >> 6;    // wave id = 8-col slab id
    const int l  = t & 63;
    const int c0 = w << 3;
    const int r0 = l, r1 = l + 64;

    v2f sv[8];   // sv[j] = (row r0, row r1) at col c0+j
    {
        const float x0 = rs[(b * NM + r0) * 3 + 0];
        const float y0 = rs[(b * NM + r0) * 3 + 1];
        const float z0 = rs[(b * NM + r0) * 3 + 2];
        const float x1 = rs[(b * NM + r1) * 3 + 0];
        const float y1 = rs[(b * NM + r1) * 3 + 1];
        const float z1 = rs[(b * NM + r1) * 3 + 2];
#pragma unroll
        for (int j = 0; j < 8; ++j) {
            const int m = c0 + j;  // wave-uniform -> scalar loads
            const float kx = kpts[m * 3 + 0], ky = kpts[m * 3 + 1], kz = kpts[m * 3 + 2];
            const float cw = csw[m], sw = ssw[m];
            float sn, cn;
            __sincosf(kx * x0 + ky * y0 + kz * z0, &sn, &cn);
            sv[j].x = cw * cn - sw * sn;
            __sincosf(kx * x1 + ky * y1 + kz * z1, &sn, &cn);
            sv[j].y = cw * cn - sw * sn;
        }
    }

    bool elim0 = false, elim1 = false;

    // ---- bootstrap: wave 0 publishes steps 0 and 1 ----
    if (w == 0) {
        const float c0a = sv[0].x, c0b = sv[0].y;
        const float c1p = sv[1].x, c1q = sv[1].y;
        const unsigned key0 = argmax_bcast(pack_key(c0a, r0), pack_key(c0b, r1));
        const int p0 = (int)(key0 & 127u);
        const float piv0 = (p0 < 64) ? readlane_f(c0a, p0) : readlane_f(c0b, p0 - 64);
        const float u01  = (p0 < 64) ? readlane_f(c1p, p0) : readlane_f(c1q, p0 - 64);
        const float rcp0 = __builtin_amdgcn_rcpf(piv0);
        const bool e0 = (r0 == p0), e1 = (r1 == p0);
        const float l0a = e0 ? 0.0f : c0a * rcp0;
        const float l0b = e1 ? 0.0f : c0b * rcp0;
        const float c1a = c1p - l0a * u01;
        const float c1b = c1q - l0b * u01;
        const unsigned key1 = argmax_bcast(e0 ? 0u : pack_key(c1a, r0),
                                           e1 ? 0u : pack_key(c1b, r1));
        const int p1 = (int)(key1 & 127u);
        const float piv1 = (p1 < 64) ? readlane_f(c1a, p1) : readlane_f(c1b, p1 - 64);
        const float rcp1 = __builtin_amdgcn_rcpf(piv1);
        colv[0][r0] = make_float2(c0a * rcp0, c1a * rcp1);  // pre-multiplied, raw
        colv[0][r1] = make_float2(c0b * rcp0, c1b * rcp1);
        if (l == 0) pub[0] = make_float4(piv0, piv1,
                                         __uint_as_float(key0), __uint_as_float(key1));
    }
    __syncthreads();

    // ---- main loop: one barrier per 2 elimination steps ----
    for (int k = 0; k < NM - 2; k += 2) {
        if (c0 + 7 >= k + 2) {           // live slab; dead waves only barrier
            const int rd = k >> 1;
            const float4 pb = pub[rd];
            const int p0 = (int)(__float_as_uint(pb.z) & 127u);
            const int p1 = (int)(__float_as_uint(pb.w) & 127u);
            const float2 ca = colv[rd & 1][r0];   // pre-multiplied l-values
            const float2 cb = colv[rd & 1][r1];
            elim0 |= (r0 == p0); elim1 |= (r1 == p0);
            const float l0a = elim0 ? 0.0f : ca.x;
            const float l0b = elim1 ? 0.0f : cb.x;
            elim0 |= (r0 == p1); elim1 |= (r1 == p1);
            const float l1a = elim0 ? 0.0f : ca.y;
            const float l1b = elim1 ? 0.0f : cb.y;
            const float lp1 = colv[rd & 1][p1].x;   // exact l0[p1] (broadcast)
            const v2f lm0 = {l0a, l0b};
            const v2f lm1 = {l1a, l1b};

            const int p0u = __builtin_amdgcn_readfirstlane(p0);
            const int p1u = __builtin_amdgcn_readfirstlane(p1);
            if (p0u < 64) {
                if (p1u < 64) update8<true, true >(sv, p0u,      p1u,      lp1, lm0, lm1);
                else          update8<true, false>(sv, p0u,      p1u - 64, lp1, lm0, lm1);
            } else {
                if (p1u < 64) update8<false, true >(sv, p0u - 64, p1u,      lp1, lm0, lm1);
                else          update8<false, false>(sv, p0u - 64, p1u - 64, lp1, lm0, lm1);
            }

            // ---- look-ahead publish of steps k+2, k+3 (one owner wave) ----
            if (w == ((k + 2) >> 3)) {
                const int jb = ((k + 2) & 7) >> 1;   // uniform in [0,4)
                const v2f e0v = (jb & 1) ? sv[2] : sv[0];
                const v2f e1v = (jb & 1) ? sv[6] : sv[4];
                const v2f c2  = (jb & 2) ? e1v : e0v;
                const v2f o0v = (jb & 1) ? sv[3] : sv[1];
                const v2f o1v = (jb & 1) ? sv[7] : sv[5];
                const v2f c3  = (jb & 2) ? o1v : o0v;
                const float c2a = c2.x, c2b = c2.y;
                const float c3p = c3.x, c3q = c3.y;
                const unsigned key2 = argmax_bcast(elim0 ? 0u : pack_key(c2a, r0),
                                                   elim1 ? 0u : pack_key(c2b, r1));
                const int p2 = (int)(key2 & 127u);
                const float piv2 = (p2 < 64) ? readlane_f(c2a, p2) : readlane_f(c2b, p2 - 64);
                const float u23  = (p2 < 64) ? readlane_f(c3p, p2) : readlane_f(c3q, p2 - 64);
                const float rcp2 = __builtin_amdgcn_rcpf(piv2);
                const bool f0 = elim0 || (r0 == p2), f1 = elim1 || (r1 == p2);
                const float l2a = f0 ? 0.0f : c2a * rcp2;
                const float l2b = f1 ? 0.0f : c2b * rcp2;
                const float c3a = c3p - l2a * u23;
                const float c3b = c3q - l2b * u23;
                const unsigned key3 = argmax_bcast(f0 ? 0u : pack_key(c3a, r0),
                                                   f1 ? 0u : pack_key(c3b, r1));
                const int p3 = (int)(key3 & 127u);
                const float piv3 = (p3 < 64) ? readlane_f(c3a, p3) : readlane_f(c3b, p3 - 64);
                const float rcp3 = __builtin_amdgcn_rcpf(piv3);
                const int rdn = (rd + 1) & 1;
                colv[rdn][r0] = make_float2(c2a * rcp2, c3a * rcp3);
                colv[rdn][r1] = make_float2(c2b * rcp2, c3b * rcp3);
                if (l == 0) pub[rd + 1] = make_float4(piv2, piv3,
                                 __uint_as_float(key2), __uint_as_float(key3));
            }
        }
        __syncthreads();
    }

    // ---- log|det| = sum log|piv_k| over the write-once pub array ----
    float lg = 0.0f;
    if (t < NM) {
        const float4 pb = pub[t >> 1];
        const float pv = (t & 1) ? pb.y : pb.x;
        lg = __logf(fabsf(pv));
#pragma unroll
        for (int off = 32; off > 0; off >>= 1)
            lg += __shfl_xor(lg, off, 64);
        if ((t & 63) == 0) redf[t >> 6] = lg;
    }
    __syncthreads();
    if (t == 0) out[b] = redf[0] + redf[1];
}

extern "C" void kernel_launch(void* const* d_in, const int* in_sizes, int n_in,
                              void* d_out, int out_size, void* d_ws, size_t ws_size,
                              hipStream_t stream) {
    const float* rs = (const float*)d_in[0];
    const float* kp = (const float*)d_in[1];
    const float* cs = (const float*)d_in[2];
    const float* ss = (const float*)d_in[3];
    float* out = (float*)d_out;
    const int batch = in_sizes[0] / (NM * 3);  // 4096
    slater_logdet<<<dim3(batch), dim3(NT), 0, stream>>>(rs, kp, cs, ss, out);
}

// Round 8
// 533.024 us; speedup vs baseline: 2.8848x; 1.0495x over previous
//
#include <hip/hip_runtime.h>
#include <stdint.h>

#define NM 128    // matrix dim / electrons
#define NT 1024   // 16 waves; wave w owns cols [8w..8w+7]; lane l owns rows l, l+64
                  // lane state: sv[j] = (S[l][8w+j], S[l+64][8w+j])

typedef float v2f __attribute__((ext_vector_type(2)));

__device__ __forceinline__ float readlane_f(float v, int lane) {
    return __int_as_float(__builtin_amdgcn_readlane(__float_as_int(v), lane));
}

// Full 64-lane unsigned max via DPP (VALU pipe); result valid in lane 63.
__device__ __forceinline__ unsigned wave_max_dpp(unsigned x) {
    int v = (int)x;
#define DPP_STEP(ctrl) \
    { int o = __builtin_amdgcn_update_dpp(0, v, ctrl, 0xf, 0xf, true); \
      v = ((unsigned)o > (unsigned)v) ? o : v; }
    DPP_STEP(0x111)  // row_shr:1
    DPP_STEP(0x112)  // row_shr:2
    DPP_STEP(0x114)  // row_shr:4
    DPP_STEP(0x118)  // row_shr:8
    DPP_STEP(0x142)  // row_bcast:15
    DPP_STEP(0x143)  // row_bcast:31
#undef DPP_STEP
    return (unsigned)v;
}

__device__ __forceinline__ unsigned pack_key(float v, int r) {
    // monotone in |v|; drop 6 mantissa LSBs to make room for the 7-bit row id
    return (((__float_as_uint(v) & 0x7fffffffu) >> 6) << 7) | (unsigned)r;
}

// max(ka,kb) over the wave, broadcast to all lanes (uniform result)
__device__ __forceinline__ unsigned argmax_bcast(unsigned ka, unsigned kb) {
    const unsigned m = wave_max_dpp(ka > kb ? ka : kb);
    return (unsigned)__builtin_amdgcn_readlane((int)m, 63);
}

// Interleaved rank-2 update of an 8-col slab. Step k applied BEFORE reading
// u1: row p1's registers already hold post-step-k values, so no fixup FMA.
// lm0/lm1 are pre-multiplied AND pre-zeroed (publisher applied elim masking).
template<bool P0LO, bool P1LO>
__device__ __forceinline__ void update8(v2f (&sv)[8], int p0l, int p1l,
                                        v2f lm0, v2f lm1) {
#pragma unroll
    for (int j = 0; j < 8; ++j) {
        const float u0 = P0LO ? readlane_f(sv[j].x, p0l) : readlane_f(sv[j].y, p0l);
        sv[j] = __builtin_elementwise_fma((v2f){-u0, -u0}, lm0, sv[j]);
        const float u1 = P1LO ? readlane_f(sv[j].x, p1l) : readlane_f(sv[j].y, p1l);
        sv[j] = __builtin_elementwise_fma((v2f){-u1, -u1}, lm1, sv[j]);
    }
}

__global__ __launch_bounds__(NT, 8)
void slater_logdet(const float* __restrict__ rs,
                   const float* __restrict__ kpts,
                   const float* __restrict__ csw,
                   const float* __restrict__ ssw,
                   float* __restrict__ out) {
    // colv[parity][step 0/1][row]: PRE-MULTIPLIED, PRE-ZEROED multipliers
    __shared__ float  colv[2][2][NM];
    __shared__ uint2  keys[NM / 2];   // write-once pivot-id keys per round
    __shared__ float2 pivs[NM / 2];   // write-once exact pivots (epilogue log)
    __shared__ float  redf[2];

    const int t  = threadIdx.x;
    const int b  = blockIdx.x;
    const int w  = t >> 6;    // wave id = 8-col slab id
    const int l  = t & 63;
    const int c0 = w << 3;
    const int r0 = l, r1 = l + 64;

    v2f sv[8];   // sv[j] = (row r0, row r1) at col c0+j
    {
        const float x0 = rs[(b * NM + r0) * 3 + 0];
        const float y0 = rs[(b * NM + r0) * 3 + 1];
        const float z0 = rs[(b * NM + r0) * 3 + 2];
        const float x1 = rs[(b * NM + r1) * 3 + 0];
        const float y1 = rs[(b * NM + r1) * 3 + 1];
        const float z1 = rs[(b * NM + r1) * 3 + 2];
#pragma unroll
        for (int j = 0; j < 8; ++j) {
            const int m = c0 + j;  // wave-uniform -> scalar loads
            const float kx = kpts[m * 3 + 0], ky = kpts[m * 3 + 1], kz = kpts[m * 3 + 2];
            const float cw = csw[m], sw = ssw[m];
            float sn, cn;
            __sincosf(kx * x0 + ky * y0 + kz * z0, &sn, &cn);
            sv[j].x = cw * cn - sw * sn;
            __sincosf(kx * x1 + ky * y1 + kz * z1, &sn, &cn);
            sv[j].y = cw * cn - sw * sn;
        }
    }

    bool elim0 = false, elim1 = false;

    // ---- bootstrap: wave 0 publishes round 0 (steps 0,1) ----
    if (w == 0) {
        const float c0a = sv[0].x, c0b = sv[0].y;
        const float c1p = sv[1].x, c1q = sv[1].y;
        const unsigned key0 = argmax_bcast(pack_key(c0a, r0), pack_key(c0b, r1));
        const int p0 = (int)(key0 & 127u);
        const float piv0 = (p0 < 64) ? readlane_f(c0a, p0) : readlane_f(c0b, p0 - 64);
        const float u01  = (p0 < 64) ? readlane_f(c1p, p0) : readlane_f(c1q, p0 - 64);
        const float rcp0 = __builtin_amdgcn_rcpf(piv0);
        const bool e0 = (r0 == p0), e1 = (r1 == p0);
        const float l0a = e0 ? 0.0f : c0a * rcp0;
        const float l0b = e1 ? 0.0f : c0b * rcp0;
        const float c1a = c1p - l0a * u01;
        const float c1b = c1q - l0b * u01;
        const unsigned key1 = argmax_bcast(e0 ? 0u : pack_key(c1a, r0),
                                           e1 ? 0u : pack_key(c1b, r1));
        const int p1 = (int)(key1 & 127u);
        const float piv1 = (p1 < 64) ? readlane_f(c1a, p1) : readlane_f(c1b, p1 - 64);
        const float rcp1 = __builtin_amdgcn_rcpf(piv1);
        const bool f0 = e0 || (r0 == p1), f1 = e1 || (r1 == p1);
        colv[0][0][r0] = l0a;
        colv[0][0][r1] = l0b;
        colv[0][1][r0] = f0 ? 0.0f : c1a * rcp1;
        colv[0][1][r1] = f1 ? 0.0f : c1b * rcp1;
        if (l == 0) { keys[0] = make_uint2(key0, key1);
                      pivs[0] = make_float2(piv0, piv1); }
    }
    __syncthreads();

    // ---- main loop: one barrier per 2 steps; dead waves drop to barrier-only ----
    const int lastLive = 4 * w + 2;             // final round = final ownership round
    const int liveEnd  = lastLive < 62 ? lastLive : 62;
    int rd = 0;
    for (; rd <= liveEnd; ++rd) {
        const uint2 kk = keys[rd];
        const int p0u = __builtin_amdgcn_readfirstlane((int)(kk.x & 127u));
        const int p1u = __builtin_amdgcn_readfirstlane((int)(kk.y & 127u));
        elim0 |= (r0 == p0u) | (r0 == p1u);     // scalar-mask bookkeeping only
        elim1 |= (r1 == p0u) | (r1 == p1u);

        const float* cva = &colv[rd & 1][0][0];
        const float* cvb = &colv[rd & 1][1][0];
        const v2f lm0 = { cva[r0], cva[r1] };   // pre-zeroed premultipliers
        const v2f lm1 = { cvb[r0], cvb[r1] };

        if (p0u < 64) {
            if (p1u < 64) update8<true, true >(sv, p0u,      p1u,      lm0, lm1);
            else          update8<true, false>(sv, p0u,      p1u - 64, lm0, lm1);
        } else {
            if (p1u < 64) update8<false, true >(sv, p0u - 64, p1u,      lm0, lm1);
            else          update8<false, false>(sv, p0u - 64, p1u - 64, lm0, lm1);
        }

        // ---- look-ahead publish of round rd+1 (one owner wave) ----
        const int k2 = 2 * rd + 2;
        if (w == (k2 >> 3)) {
            const int jb = (k2 & 7) >> 1;        // uniform in [0,4)
            const v2f e0v = (jb & 1) ? sv[2] : sv[0];
            const v2f e1v = (jb & 1) ? sv[6] : sv[4];
            const v2f c2  = (jb & 2) ? e1v : e0v;
            const v2f o0v = (jb & 1) ? sv[3] : sv[1];
            const v2f o1v = (jb & 1) ? sv[7] : sv[5];
            const v2f c3  = (jb & 2) ? o1v : o0v;
            const unsigned key2 = argmax_bcast(elim0 ? 0u : pack_key(c2.x, r0),
                                               elim1 ? 0u : pack_key(c2.y, r1));
            const int p2 = (int)(key2 & 127u);
            const float piv2 = (p2 < 64) ? readlane_f(c2.x, p2) : readlane_f(c2.y, p2 - 64);
            const float u23  = (p2 < 64) ? readlane_f(c3.x, p2) : readlane_f(c3.y, p2 - 64);
            const float rcp2 = __builtin_amdgcn_rcpf(piv2);
            const bool f0 = elim0 || (r0 == p2), f1 = elim1 || (r1 == p2);
            const float l2a = f0 ? 0.0f : c2.x * rcp2;
            const float l2b = f1 ? 0.0f : c2.y * rcp2;
            const float c3a = c3.x - l2a * u23;
            const float c3b = c3.y - l2b * u23;
            const unsigned key3 = argmax_bcast(f0 ? 0u : pack_key(c3a, r0),
                                               f1 ? 0u : pack_key(c3b, r1));
            const int p3 = (int)(key3 & 127u);
            const float piv3 = (p3 < 64) ? readlane_f(c3a, p3) : readlane_f(c3b, p3 - 64);
            const float rcp3 = __builtin_amdgcn_rcpf(piv3);
            const bool g0 = f0 || (r0 == p3), g1 = f1 || (r1 == p3);
            const int pn = (rd + 1) & 1;
            colv[pn][0][r0] = l2a;
            colv[pn][0][r1] = l2b;
            colv[pn][1][r0] = g0 ? 0.0f : c3a * rcp3;
            colv[pn][1][r1] = g1 ? 0.0f : c3b * rcp3;
            if (l == 0) { keys[rd + 1] = make_uint2(key2, key3);
                          pivs[rd + 1] = make_float2(piv2, piv3); }
        }
        __syncthreads();
    }
    for (; rd < 63; ++rd) __syncthreads();   // dead waves: barrier-only

    // ---- log|det| = sum log|piv_k| over the write-once pivs array ----
    float lg = 0.0f;
    if (t < NM) {
        const float2 pv2 = pivs[t >> 1];
        lg = __logf(fabsf((t & 1) ? pv2.y : pv2.x));
#pragma unroll
        for (int off = 32; off > 0; off >>= 1)
            lg += __shfl_xor(lg, off, 64);
        if ((t & 63) == 0) redf[t >> 6] = lg;
    }
    __syncthreads();
    if (t == 0) out[b] = redf[0] + redf[1];
}

extern "C" void kernel_launch(void* const* d_in, const int* in_sizes, int n_in,
                              void* d_out, int out_size, void* d_ws, size_t ws_size,
                              hipStream_t stream) {
    const float* rs = (const float*)d_in[0];
    const float* kp = (const float*)d_in[1];
    const float* cs = (const float*)d_in[2];
    const float* ss = (const float*)d_in[3];
    float* out = (float*)d_out;
    const int batch = in_sizes[0] / (NM * 3);  // 4096
    slater_logdet<<<dim3(batch), dim3(NT), 0, stream>>>(rs, kp, cs, ss, out);
}